// Round 11
// baseline (1539.800 us; speedup 1.0000x reference)
//
#include <hip/hip_runtime.h>
#include <hip/hip_bf16.h>
#include <cstddef>

#define T_ 64
#define N_ 1024
#define L_ 16
#define H_ 256
#define STATE_ 290
#define EKSTR 296   // enc hbf row stride (ushorts): 592B = 37*16, b128-aligned

typedef short s16x8 __attribute__((ext_vector_type(8)));
typedef float f32x4 __attribute__((ext_vector_type(4)));
typedef ushort us4 __attribute__((ext_vector_type(4)));
typedef ushort us8 __attribute__((ext_vector_type(8)));
#define MFMA16 __builtin_amdgcn_mfma_f32_16x16x32_bf16

// raw barrier: wait LDS ops only, do NOT drain global stores.
#define BAR() asm volatile("s_waitcnt lgkmcnt(0)\n\ts_barrier" ::: "memory")

__device__ __forceinline__ float b2f(ushort u){ return __uint_as_float(((unsigned)u) << 16); }
__device__ __forceinline__ ushort f2b(float f){
  unsigned x = __float_as_uint(f);
  return (ushort)((x + 0x7FFFu + ((x >> 16) & 1u)) >> 16);
}
__device__ __forceinline__ float gruh(float gir,float giz,float gig,
                                      float ghr,float ghz,float ghg,float hp){
  float r = 1.f/(1.f + __expf(-(gir + ghr)));
  float z = 1.f/(1.f + __expf(-(giz + ghz)));
  float g = tanhf(gig + r*ghg);
  return (1.f - z)*g + z*hp;
}

// ---------- conversion / prep kernels ----------
__global__ void conv_pad_b(const float* __restrict__ src, ushort* __restrict__ dst,
                           int R, int C, int Cp, int total){
  int idx = blockIdx.x*256 + threadIdx.x;
  if (idx >= total) return;
  int r = idx / Cp, c = idx - r*Cp;
  dst[idx] = (r < R && c < C) ? f2b(src[(size_t)r*C + c]) : (ushort)0;
}
__global__ void perm_enc_w(const float* __restrict__ src, ushort* __restrict__ dst,
                           int Ci, int Cp, int total){
  int idx = blockIdx.x*256 + threadIdx.x;
  if (idx >= total) return;
  int d = idx / Cp, c = idx - d*Cp;
  int tile = d >> 4, u = d & 15;
  int k = tile / 3, p = tile - 3*k;
  int hc = k*16 + u;
  bool ok = (tile < 51) && (hc < 257) && (c < Ci);
  dst[idx] = ok ? f2b(src[(size_t)(p*257 + hc)*Ci + c]) : (ushort)0;
}
__global__ void perm_cell_w(const float* __restrict__ src, ushort* __restrict__ dst){
  int idx = blockIdx.x*256 + threadIdx.x;
  if (idx >= 768*256) return;
  int d = idx >> 8, c = idx & 255;
  int tile = d >> 4, u = d & 15;
  int k = tile / 3, p = tile - 3*k;
  dst[idx] = f2b(src[(size_t)(p*256 + k*16 + u)*256 + c]);
}
__global__ void cbias_k(const float* __restrict__ bih, const float* __restrict__ bhh,
                        float* __restrict__ cb){
  int d = blockIdx.x*256 + threadIdx.x;
  if (d >= 768) return;
  int tile = d >> 4, u = d & 15;
  int k = tile / 3, p = tile - 3*k;
  int src = p*256 + k*16 + u;
  cb[d] = bih[src] + (p < 2 ? bhh[src] : 0.f);
}
__global__ void transp_b(const float* __restrict__ Wa, ushort* __restrict__ WaTb){
  int m = blockIdx.x, h = threadIdx.x;
  WaTb[(size_t)h*256 + m] = f2b(Wa[(size_t)m*256 + h]);
}
__global__ void embed_b(const int* __restrict__ lines, const float* __restrict__ emb,
                        ushort* __restrict__ Mbf){
  size_t idx = (size_t)blockIdx.x*256 + threadIdx.x;
  if (idx >= (size_t)N_*L_*H_) return;
  int c = idx & 255; size_t nl = idx >> 8;
  Mbf[idx] = f2b(emb[(size_t)lines[nl]*256 + c]);
}
__global__ void init_state(const float* __restrict__ hxs, float* __restrict__ hbuf,
                           float* __restrict__ p0){
  int n = blockIdx.x, t = threadIdx.x;
  __shared__ int nz;
  if (t == 0) nz = 0;
  __syncthreads();
  for (int c = t; c < STATE_; c += 256)
    if (hxs[(size_t)n*STATE_ + c] != 0.f) atomicOr(&nz, 1);
  __syncthreads();
  bool new_ep = (nz == 0);
  for (int c = t; c < H_; c += 256) hbuf[(size_t)n*H_ + c] = hxs[(size_t)n*STATE_ + 2 + c];
  if (t < L_) {
    float pv = hxs[(size_t)n*STATE_ + 2 + H_ + L_ + t];
    if (t == 0 && new_ep) pv = 1.f;
    p0[n*L_ + t] = pv;
  }
}
__global__ void r0_kernel(const float* __restrict__ p0, const ushort* __restrict__ Mbf,
                          float* __restrict__ r0v){
  int n = blockIdx.x, c = threadIdx.x;
  float s = 0.f;
  for (int l = 0; l < 16; ++l) s += p0[n*16 + l]*b2f(Mbf[((size_t)n*16 + l)*256 + c]);
  r0v[(size_t)n*256 + c] = s;
}
__global__ void build_xcat8(const float* __restrict__ cond, const int* __restrict__ act,
                            const float* __restrict__ r0v, const ushort* __restrict__ Mbf,
                            ushort* __restrict__ xcat){
  int idx = blockIdx.x*256 + threadIdx.x;
  if (idx >= T_*N_*40) return;
  int kc = idx % 40;
  int row = idx / 40;
  int n = row & 1023, t = row >> 10;
  us8 v;
  if (kc < 8) {
    const float* cp = cond + (size_t)row*64 + kc*8;
    #pragma unroll
    for (int i = 0; i < 8; ++i) v[i] = f2b(cp[i]);
  } else if (t == 0) {
    const float* rp = r0v + (size_t)n*256 + (kc-8)*8;
    #pragma unroll
    for (int i = 0; i < 8; ++i) v[i] = f2b(rp[i]);
  } else {
    int a = act[(size_t)(t-1)*1024 + n];
    v = *(const us8*)(Mbf + ((size_t)n*16 + a)*256 + (kc-8)*8);
  }
  *(us8*)(xcat + (size_t)idx*8) = v;
}

// ---------- MFMA GEMM: out[r,col] = act(sum_k A[r,k]*W[col,k] + bias[col]), bf16 out ----------
template<int RELU>
__global__ __launch_bounds__(256) void gemm_mfma(
    const ushort* __restrict__ A, const ushort* __restrict__ W,
    const float* __restrict__ bias, ushort* __restrict__ out,
    int Kd, int ldo){
  int lane = threadIdx.x & 63, wv = threadIdx.x >> 6;
  int u = lane & 15, g4 = lane >> 4;
  int br = blockIdx.x*64 + wv*16;
  int bm = blockIdx.y*64;
  const ushort* Arow = A + (size_t)(br + u)*Kd + g4*8;
  f32x4 acc0 = {0,0,0,0}, acc1 = {0,0,0,0}, acc2 = {0,0,0,0}, acc3 = {0,0,0,0};
  for (int k0 = 0; k0 < Kd; k0 += 32) {
    s16x8 av = *(const s16x8*)(Arow + k0);
    s16x8 b0 = *(const s16x8*)(W + (size_t)(bm +  0 + u)*Kd + k0 + g4*8);
    s16x8 b1 = *(const s16x8*)(W + (size_t)(bm + 16 + u)*Kd + k0 + g4*8);
    s16x8 b2 = *(const s16x8*)(W + (size_t)(bm + 32 + u)*Kd + k0 + g4*8);
    s16x8 b3 = *(const s16x8*)(W + (size_t)(bm + 48 + u)*Kd + k0 + g4*8);
    acc0 = MFMA16(av, b0, acc0, 0,0,0);
    acc1 = MFMA16(av, b1, acc1, 0,0,0);
    acc2 = MFMA16(av, b2, acc2, 0,0,0);
    acc3 = MFMA16(av, b3, acc3, 0,0,0);
  }
  f32x4 ac[4] = {acc0, acc1, acc2, acc3};
  #pragma unroll
  for (int mt = 0; mt < 4; ++mt) {
    int col = bm + mt*16 + u;
    float b = bias ? bias[col] : 0.f;
    #pragma unroll
    for (int r = 0; r < 4; ++r) {
      float v = ac[mt][r] + b;
      if (RELU) v = fmaxf(v, 0.f);
      out[(size_t)(br + g4*4 + r)*ldo + col] = f2b(v);
    }
  }
}

// ---------- unified encoder: fwd triangular chains + bwd chain in one kernel ----------
// 256 blocks (4 batch rows each) x 8 waves; __launch_bounds__(512,2) -> 256 VGPR budget
// (1 block/CU), acc[5][2][3]=120 VGPR stays in registers (round-10's 128-cap spilled it).
__global__ __launch_bounds__(512, 2) void enc_all(
    const ushort* __restrict__ GiAll, const ushort* __restrict__ Wh,
    const float* __restrict__ bih, const float* __restrict__ bhh,
    float* __restrict__ Km, float* __restrict__ Cm, ushort* __restrict__ Bbf){
  __shared__ __align__(16) ushort hbf[2][80][EKSTR];   // 94,720 B
  __shared__ __align__(16) ushort gis[2][2][4][832];   // 26,624 B  [buf][fwd/bwd][nl][col]
  int tid = threadIdx.x, lane = tid & 63, wv = tid >> 6;
  int u = lane & 15, g4 = lane >> 4;
  int nb = blockIdx.x * 4;
  for (int i = tid; i < 2*80*EKSTR; i += 512) ((ushort*)hbf)[i] = 0;
  #pragma unroll
  for (int i0 = 0; i0 < 4; ++i0) {
    int i = tid + i0*512;
    if (i < 1664) {
      int flat = i*4;
      int fb = flat / 3328, rem = flat - fb*3328;
      int nl = rem / 832, k = rem - nl*832;
      int row = (nb+nl)*16 + (fb ? 15 : 0);
      *(us4*)&gis[0][fb][nl][k] = *(const us4*)(GiAll + (size_t)row*832 + k);
    }
  }
  BAR();
  int cur = 0;
  for (int j = 0; j < 16; ++j) {
    // prefetch next step's gi rows (fwd j+1, bwd 14-j) into the other buffer
    if (j < 15) {
      #pragma unroll
      for (int i0 = 0; i0 < 4; ++i0) {
        int i = tid + i0*512;
        if (i < 1664) {
          int flat = i*4;
          int fb = flat / 3328, rem = flat - fb*3328;
          int nl = rem / 832, k = rem - nl*832;
          int row = (nb+nl)*16 + (fb ? (14-j) : (j+1));
          *(us4*)&gis[cur^1][fb][nl][k] = *(const us4*)(GiAll + (size_t)row*832 + k);
        }
      }
    }
    // ---- main pair of col-tiles ----
    {
      int ktA = 2*wv, ktB = 2*wv + 1;
      f32x4 acc[5][2][3];
      #pragma unroll
      for (int rt = 0; rt < 5; ++rt)
        #pragma unroll
        for (int tt = 0; tt < 2; ++tt)
          #pragma unroll
          for (int g = 0; g < 3; ++g) acc[rt][tt][g] = (f32x4){0,0,0,0};
      #pragma unroll
      for (int q = 0; q < 9; ++q) {
        int off = q*32 + g4*8;
        s16x8 wA0 = *(const s16x8*)(Wh + (size_t)((3*ktA+0)*16 + u)*288 + off);
        s16x8 wA1 = *(const s16x8*)(Wh + (size_t)((3*ktA+1)*16 + u)*288 + off);
        s16x8 wA2 = *(const s16x8*)(Wh + (size_t)((3*ktA+2)*16 + u)*288 + off);
        s16x8 wB0 = *(const s16x8*)(Wh + (size_t)((3*ktB+0)*16 + u)*288 + off);
        s16x8 wB1 = *(const s16x8*)(Wh + (size_t)((3*ktB+1)*16 + u)*288 + off);
        s16x8 wB2 = *(const s16x8*)(Wh + (size_t)((3*ktB+2)*16 + u)*288 + off);
        #pragma unroll
        for (int rt = 0; rt < 5; ++rt) {
          if (rt < 4 && rt*4 > j) continue;
          s16x8 av = *(const s16x8*)&hbf[cur][rt*16 + u][off];
          acc[rt][0][0] = MFMA16(av, wA0, acc[rt][0][0], 0,0,0);
          acc[rt][0][1] = MFMA16(av, wA1, acc[rt][0][1], 0,0,0);
          acc[rt][0][2] = MFMA16(av, wA2, acc[rt][0][2], 0,0,0);
          acc[rt][1][0] = MFMA16(av, wB0, acc[rt][1][0], 0,0,0);
          acc[rt][1][1] = MFMA16(av, wB1, acc[rt][1][1], 0,0,0);
          acc[rt][1][2] = MFMA16(av, wB2, acc[rt][1][2], 0,0,0);
        }
      }
      #pragma unroll
      for (int tt = 0; tt < 2; ++tt) {
        int kt = 2*wv + tt;
        int c = kt*16 + u;                     // < 256 always here
        float bi0 = bih[c], bi1 = bih[257+c], bi2 = bih[514+c];
        float bh0 = bhh[c], bh1 = bhh[257+c], bh2 = bhh[514+c];
        float kmP[4] = {0.f, 0.f, 0.f, 0.f};
        #pragma unroll
        for (int rt = 0; rt < 4; ++rt) {
          int ii = rt*4 + g4;
          if (rt*4 <= j && ii <= j) {
            #pragma unroll
            for (int r = 0; r < 4; ++r) {
              int rowl = rt*16 + g4*4 + r;
              const ushort* gp = &gis[cur][0][r][3*kt*16];
              float hp = b2f(hbf[cur][rowl][c]);
              float h2 = gruh(b2f(gp[u]) + bi0, b2f(gp[16+u]) + bi1, b2f(gp[32+u]) + bi2,
                              acc[rt][tt][0][r] + bh0, acc[rt][tt][1][r] + bh1,
                              acc[rt][tt][2][r] + bh2, hp);
              hbf[cur^1][rowl][c] = f2b(h2);
              kmP[r] += h2;
            }
          }
        }
        #pragma unroll
        for (int r = 0; r < 4; ++r) {
          float s = kmP[r];
          s += __shfl_xor(s, 16, 64);
          s += __shfl_xor(s, 32, 64);
          if (g4 == 0) Km[((size_t)(nb+r)*16 + j)*256 + c] = s;
        }
        if (g4 == 0) {   // bwd chain rows 64..67
          #pragma unroll
          for (int r = 0; r < 4; ++r) {
            const ushort* gp = &gis[cur][1][r][3*kt*16];
            float hp = b2f(hbf[cur][64 + r][c]);
            float h2 = gruh(b2f(gp[u]) + bi0, b2f(gp[16+u]) + bi1, b2f(gp[32+u]) + bi2,
                            acc[4][tt][0][r] + bh0, acc[4][tt][1][r] + bh1,
                            acc[4][tt][2][r] + bh2, hp);
            hbf[cur^1][64 + r][c] = f2b(h2);
            Bbf[((size_t)j*1024 + nb + r)*288 + c] = f2b(h2);
          }
        }
      }
    }
    // ---- tile16 (c=256): wave w handles row-tile w (w=0..3 fwd, w=4 bwd) ----
    if (wv < 5) {
      int rt = wv;
      bool go = (rt == 4) || (rt*4 <= j);
      if (go) {
        f32x4 a0 = {0,0,0,0}, a1 = {0,0,0,0}, a2 = {0,0,0,0};
        #pragma unroll
        for (int q = 0; q < 9; ++q) {
          int off = q*32 + g4*8;
          s16x8 w0 = *(const s16x8*)(Wh + (size_t)(48*16 + u)*288 + off);
          s16x8 w1 = *(const s16x8*)(Wh + (size_t)(49*16 + u)*288 + off);
          s16x8 w2 = *(const s16x8*)(Wh + (size_t)(50*16 + u)*288 + off);
          s16x8 av = *(const s16x8*)&hbf[cur][rt*16 + u][off];
          a0 = MFMA16(av, w0, a0, 0,0,0);
          a1 = MFMA16(av, w1, a1, 0,0,0);
          a2 = MFMA16(av, w2, a2, 0,0,0);
        }
        if (u == 0) {
          float bi0 = bih[256], bi1 = bih[513], bi2 = bih[770];
          float bh0 = bhh[256], bh1 = bhh[513], bh2 = bhh[770];
          if (rt < 4) {
            int ii = rt*4 + g4;
            if (ii <= j) {
              #pragma unroll
              for (int r = 0; r < 4; ++r) {
                int rowl = rt*16 + g4*4 + r;
                const ushort* gp = &gis[cur][0][r][768];
                float hp = b2f(hbf[cur][rowl][256]);
                float h2 = gruh(b2f(gp[0]) + bi0, b2f(gp[16]) + bi1, b2f(gp[32]) + bi2,
                                a0[r] + bh0, a1[r] + bh1, a2[r] + bh2, hp);
                hbf[cur^1][rowl][256] = f2b(h2);
                Cm[(size_t)(nb+r)*256 + ii*16 + j] = h2;
              }
            }
          } else if (g4 == 0) {
            #pragma unroll
            for (int r = 0; r < 4; ++r) {
              const ushort* gp = &gis[cur][1][r][768];
              float hp = b2f(hbf[cur][64 + r][256]);
              float h2 = gruh(b2f(gp[0]) + bi0, b2f(gp[16]) + bi1, b2f(gp[32]) + bi2,
                              a0[r] + bh0, a1[r] + bh1, a2[r] + bh2, hp);
              hbf[cur^1][64 + r][256] = f2b(h2);
              Bbf[((size_t)j*1024 + nb + r)*288 + 256] = f2b(h2);
            }
          }
        }
      }
    }
    BAR();
    cur ^= 1;
  }
}

// ---------- backward-part K accumulate + bf16 copy + C fill (i>j) ----------
__global__ void accum_bwd(const ushort* __restrict__ Bbf, float* __restrict__ Km,
                          ushort* __restrict__ Kmbf, float* __restrict__ Cm){
  int n = blockIdx.x, c = threadIdx.x;
  float s = 0.f;
  for (int jj = 15; jj >= 0; --jj) {
    if (jj < 15) s += b2f(Bbf[((size_t)(14-jj)*1024 + n)*288 + c]);
    size_t o = ((size_t)n*16 + jj)*256 + c;
    float v = Km[o] + s;
    Km[o] = v;
    Kmbf[o] = f2b(v);
  }
  int i = c >> 4, j = c & 15;
  if (i > j) Cm[(size_t)n*256 + i*16 + j] = b2f(Bbf[((size_t)(i-1-j)*1024 + n)*288 + 256]);
}
__global__ void wb_kernel(const float* __restrict__ Km, const float* __restrict__ ba,
                          float* __restrict__ wbv){
  int n = blockIdx.x, t = threadIdx.x;
  int l = t >> 4, lane = t & 15;
  float s = 0.f;
  for (int m = lane; m < 256; m += 16) s += Km[((size_t)n*16 + l)*256 + m]*ba[m];
  s += __shfl_down(s, 8, 16); s += __shfl_down(s, 4, 16);
  s += __shfl_down(s, 2, 16); s += __shfl_down(s, 1, 16);
  if (lane == 0) wbv[n*16 + l] = s;
}

// ---------- cell chunk: 16 t-steps, weight-stationary (Wh in VGPRs) ----------
// __launch_bounds__(512,2): 256 VGPR budget so the 192-VGPR weight preload stays resident
// (rounds 7-10's 128-cap silently spilled it -> the whole point of the design was lost).
__global__ __launch_bounds__(512, 2) void cell_chunk(
    const ushort* __restrict__ Gi, const ushort* __restrict__ Wh,
    const float* __restrict__ bhh, const float* __restrict__ hbuf,
    int t0, ushort* __restrict__ hcT, float* __restrict__ out){
  __shared__ __align__(16) ushort hbf[2][16][266];
  int tid = threadIdx.x, lane = tid & 63, wv = tid >> 6;
  int u = lane & 15, g4 = lane >> 4;
  int n0 = blockIdx.x * 16;
  int ktA = wv, ktB = wv + 8;
  int cA = ktA*16 + u, cB = ktB*16 + u;
  s16x8 WA0[8], WA1[8], WA2[8], WB0[8], WB1[8], WB2[8];
  #pragma unroll
  for (int q = 0; q < 8; ++q) {
    int off = q*32 + g4*8;
    WA0[q] = *(const s16x8*)(Wh + (size_t)((3*ktA+0)*16 + u)*256 + off);
    WA1[q] = *(const s16x8*)(Wh + (size_t)((3*ktA+1)*16 + u)*256 + off);
    WA2[q] = *(const s16x8*)(Wh + (size_t)((3*ktA+2)*16 + u)*256 + off);
    WB0[q] = *(const s16x8*)(Wh + (size_t)((3*ktB+0)*16 + u)*256 + off);
    WB1[q] = *(const s16x8*)(Wh + (size_t)((3*ktB+1)*16 + u)*256 + off);
    WB2[q] = *(const s16x8*)(Wh + (size_t)((3*ktB+2)*16 + u)*256 + off);
  }
  float bhgA = bhh[512 + cA], bhgB = bhh[512 + cB];
  if (t0 == 0) {
    for (int i = tid; i < 16*256; i += 512) {
      int rr = i >> 8, cc = i & 255;
      hbf[0][rr][cc] = f2b(hbuf[(size_t)(n0 + rr)*256 + cc]);
    }
  } else {
    for (int i = tid; i < 16*256; i += 512) {
      int rr = i >> 8, cc = i & 255;
      hbf[0][rr][cc] = hcT[((size_t)(t0-1)*1024 + n0 + rr)*256 + cc];
    }
  }
  BAR();
  int cur = 0;
  for (int s = 0; s < 16; ++s) {
    int t = t0 + s;
    f32x4 a0={0,0,0,0},a1={0,0,0,0},a2={0,0,0,0};
    f32x4 b0={0,0,0,0},b1={0,0,0,0},b2={0,0,0,0};
    #pragma unroll
    for (int q = 0; q < 8; ++q) {
      s16x8 ah = *(const s16x8*)&hbf[cur][u][q*32 + g4*8];
      a0 = MFMA16(ah, WA0[q], a0, 0,0,0);
      a1 = MFMA16(ah, WA1[q], a1, 0,0,0);
      a2 = MFMA16(ah, WA2[q], a2, 0,0,0);
      b0 = MFMA16(ah, WB0[q], b0, 0,0,0);
      b1 = MFMA16(ah, WB1[q], b1, 0,0,0);
      b2 = MFMA16(ah, WB2[q], b2, 0,0,0);
    }
    const ushort* gbase = Gi + (size_t)s*1024*768;
    #pragma unroll
    for (int r = 0; r < 4; ++r) {
      int row = g4*4 + r;
      const ushort* gr = gbase + (size_t)(n0 + row)*768;
      {
        float gir = b2f(gr[3*ktA*16 + u]);
        float giz = b2f(gr[3*ktA*16 + 16 + u]);
        float gig = b2f(gr[3*ktA*16 + 32 + u]);
        float hp  = b2f(hbf[cur][row][cA]);
        float rr2 = 1.f/(1.f + __expf(-(gir + a0[r])));
        float zz  = 1.f/(1.f + __expf(-(giz + a1[r])));
        float ex  = __expf(2.f*(gig + rr2*(a2[r] + bhgA)));
        float gg  = 1.f - 2.f/(ex + 1.f);
        float h2  = (1.f - zz)*gg + zz*hp;
        ushort hb = f2b(h2);
        hbf[cur^1][row][cA] = hb;
        hcT[((size_t)t*1024 + n0 + row)*256 + cA] = hb;
        out[((size_t)t*1024 + n0 + row)*STATE_ + 2 + cA] = h2;
        if (t == 63) out[((size_t)64*1024 + n0 + row)*STATE_ + 2 + cA] = h2;
      }
      {
        float gir = b2f(gr[3*ktB*16 + u]);
        float giz = b2f(gr[3*ktB*16 + 16 + u]);
        float gig = b2f(gr[3*ktB*16 + 32 + u]);
        float hp  = b2f(hbf[cur][row][cB]);
        float rr2 = 1.f/(1.f + __expf(-(gir + b0[r])));
        float zz  = 1.f/(1.f + __expf(-(giz + b1[r])));
        float ex  = __expf(2.f*(gig + rr2*(b2[r] + bhgB)));
        float gg  = 1.f - 2.f/(ex + 1.f);
        float h2  = (1.f - zz)*gg + zz*hp;
        ushort hb = f2b(h2);
        hbf[cur^1][row][cB] = hb;
        hcT[((size_t)t*1024 + n0 + row)*256 + cB] = hb;
        out[((size_t)t*1024 + n0 + row)*STATE_ + 2 + cB] = h2;
        if (t == 63) out[((size_t)64*1024 + n0 + row)*STATE_ + 2 + cB] = h2;
      }
    }
    BAR();
    cur ^= 1;
  }
}

// ---------- v & a columns: one wave per output row ----------
__global__ __launch_bounds__(256) void v_out(
    const ushort* __restrict__ hcT, const int* __restrict__ act,
    const float* __restrict__ Wc, const float* __restrict__ bc,
    float* __restrict__ out){
  int rowid = blockIdx.x*4 + (threadIdx.x >> 6);
  if (rowid >= 65*1024) return;
  int lane = threadIdx.x & 63;
  int tt = rowid >> 10, n = rowid & 1023;
  int t = tt > 63 ? 63 : tt;
  us4 hv = *(const us4*)(hcT + ((size_t)t*1024 + n)*256 + lane*4);
  f32x4 wv4 = *(const f32x4*)(Wc + lane*4);
  float s = b2f(hv[0])*wv4[0] + b2f(hv[1])*wv4[1] + b2f(hv[2])*wv4[2] + b2f(hv[3])*wv4[3];
  #pragma unroll
  for (int off = 32; off > 0; off >>= 1) s += __shfl_xor(s, off, 64);
  if (lane == 0) {
    size_t ro = (size_t)rowid*STATE_;
    out[ro]     = (float)act[(size_t)t*1024 + n];
    out[ro + 1] = s + bc[0];
  }
}

// ---------- batched attention/softmax post-pass ----------
__global__ __launch_bounds__(256) void attn_batch(
    const ushort* __restrict__ Ktl, const ushort* __restrict__ hcT,
    const float* __restrict__ wbv, const float* __restrict__ Cm,
    const float* __restrict__ p0, const int* __restrict__ act,
    float* __restrict__ out){
  int n = blockIdx.x;
  int lane = threadIdx.x & 63, wv = threadIdx.x >> 6;
  int u = lane & 15, g4 = lane >> 4;
  int t0 = wv*16;
  const ushort* Ka = Ktl + ((size_t)n*16 + u)*256 + g4*8;
  const ushort* Hb = hcT + ((size_t)(t0 + u)*1024 + n)*256 + g4*8;
  f32x4 acc = {0,0,0,0};
  #pragma unroll
  for (int q = 0; q < 8; ++q) {
    s16x8 av = *(const s16x8*)(Ka + q*32);
    s16x8 bv = *(const s16x8*)(Hb + q*32);
    acc = MFMA16(av, bv, acc, 0,0,0);
  }
  int t = t0 + u;
  float ps[4];
  if (t == 0) {
    #pragma unroll
    for (int r = 0; r < 4; ++r) {
      float catt = 0.f;
      for (int i = 0; i < 16; ++i) catt += p0[n*16 + i]*Cm[(size_t)n*256 + i*16 + g4*4 + r];
      ps[r] = (acc[r] + wbv[n*16 + g4*4 + r]) * catt;
    }
  } else {
    int ap = act[(size_t)(t-1)*1024 + n];
    #pragma unroll
    for (int r = 0; r < 4; ++r)
      ps[r] = (acc[r] + wbv[n*16 + g4*4 + r]) * Cm[(size_t)n*256 + ap*16 + g4*4 + r];
  }
  float mx = fmaxf(fmaxf(ps[0], ps[1]), fmaxf(ps[2], ps[3]));
  mx = fmaxf(mx, __shfl_xor(mx, 16, 64));
  mx = fmaxf(mx, __shfl_xor(mx, 32, 64));
  float e[4], se = 0.f;
  #pragma unroll
  for (int r = 0; r < 4; ++r) { e[r] = __expf(ps[r] - mx); se += e[r]; }
  se += __shfl_xor(se, 16, 64);
  se += __shfl_xor(se, 32, 64);
  float inv = 1.f/se;
  int a = act[(size_t)t*1024 + n];
  size_t ro = ((size_t)t*1024 + n)*STATE_;
  #pragma unroll
  for (int r = 0; r < 4; ++r) {
    out[ro + 258 + g4*4 + r] = e[r]*inv;
    out[ro + 274 + g4*4 + r] = (g4*4 + r == a) ? 1.f : 0.f;
  }
  if (t == 63) {
    size_t r2 = ((size_t)64*1024 + n)*STATE_;
    #pragma unroll
    for (int r = 0; r < 4; ++r) {
      out[r2 + 258 + g4*4 + r] = e[r]*inv;
      out[r2 + 274 + g4*4 + r] = (g4*4 + r == a) ? 1.f : 0.f;
    }
  }
}

extern "C" void kernel_launch(void* const* d_in, const int* in_sizes, int n_in,
                              void* d_out, int out_size, void* d_ws, size_t ws_size,
                              hipStream_t stream){
  (void)in_sizes; (void)n_in; (void)out_size; (void)ws_size;
  const float* cond  = (const float*)d_in[0];
  const int*   lines = (const int*)  d_in[1];
  const int*   act   = (const int*)  d_in[2];
  const float* hxs   = (const float*)d_in[3];
  const float* emb   = (const float*)d_in[4];
  const float* wih_e = (const float*)d_in[5];
  const float* whh_e = (const float*)d_in[6];
  const float* bih_e = (const float*)d_in[7];
  const float* bhh_e = (const float*)d_in[8];
  const float* W1    = (const float*)d_in[9];
  const float* b1    = (const float*)d_in[10];
  const float* W2    = (const float*)d_in[11];
  const float* b2    = (const float*)d_in[12];
  const float* wih_c = (const float*)d_in[13];
  const float* whh_c = (const float*)d_in[14];
  const float* bih_c = (const float*)d_in[15];
  const float* bhh_c = (const float*)d_in[16];
  const float* Wa    = (const float*)d_in[17];
  const float* ba    = (const float*)d_in[18];
  const float* Wc    = (const float*)d_in[19];
  const float* bc    = (const float*)d_in[20];
  float* out = (float*)d_out;

  char* base = (char*)d_ws;
  ushort* Mbf    = (ushort*)(base + 0);             // [16384,256]       P0-P3
  ushort* Bbf    = (ushort*)(base + 8388608);       // [16,1024,288]     P1-P2
  float*  Km     = (float*) (base + 17825792);      // [16384,256] f32   P1-P2
  ushort* Kmbf   = (ushort*)(base + 34603008);      // [16384,256]       P2
  ushort* xcat   = (ushort*)(base + 8388608);       // [65536,320]       P3
  ushort* x2     = (ushort*)(base + 8388608);       // [65536,256]       P3
  ushort* hcT    = (ushort*)(base + 8388608);       // [64,1024,256]     P4-P5
  ushort* GiAll  = (ushort*)(base + 50331648);      // [16384,832]       P1
  ushort* x1     = (ushort*)(base + 50331648);      // [65536,256]       P3
  ushort* GiC0   = (ushort*)(base + 50331648);      // [16,1024,768]     P4
  ushort* GiC1   = (ushort*)(base + 75497472);      // [16,1024,768]     P4
  ushort* Ktl    = (ushort*)(base + 100663296);     // [16384,256]       P2-P5
  float*  Cm     = (float*) (base + 109051904);     // [1024,16,16]
  float*  hbuf   = (float*) (base + 110100480);     // [1024,256]
  float*  p0     = (float*) (base + 111149056);     // [1024,16]
  float*  r0v    = (float*) (base + 111214592);     // [1024,256]
  float*  wbv    = (float*) (base + 112263168);     // [1024,16]
  ushort* wihe_p = (ushort*)(base + 112328704);     // [832,256]
  ushort* whhe_p = (ushort*)(base + 112754688);     // [832,288]
  ushort* wihc_p = (ushort*)(base + 113233920);     // [768,256]
  ushort* whhc_p = (ushort*)(base + 113627136);     // [768,256]
  ushort* W1b    = (ushort*)(base + 114020352);     // [256,320]
  ushort* W2b    = (ushort*)(base + 114184192);     // [256,256]
  ushort* WaTb   = (ushort*)(base + 114315264);     // [256,256]
  float*  cbias  = (float*) (base + 114446336);     // [768]

  perm_enc_w<<<832, 256, 0, stream>>>(wih_e, wihe_p, 256, 256, 832*256);
  perm_enc_w<<<936, 256, 0, stream>>>(whh_e, whhe_p, 257, 288, 832*288);
  perm_cell_w<<<768, 256, 0, stream>>>(wih_c, wihc_p);
  perm_cell_w<<<768, 256, 0, stream>>>(whh_c, whhc_p);
  cbias_k<<<3, 256, 0, stream>>>(bih_c, bhh_c, cbias);
  conv_pad_b<<<320, 256, 0, stream>>>(W1, W1b, 256, 320, 320, 256*320);
  conv_pad_b<<<256, 256, 0, stream>>>(W2, W2b, 256, 256, 256, 256*256);
  transp_b<<<256, 256, 0, stream>>>(Wa, WaTb);

  embed_b<<<16384, 256, 0, stream>>>(lines, emb, Mbf);
  init_state<<<1024, 256, 0, stream>>>(hxs, hbuf, p0);
  r0_kernel<<<1024, 256, 0, stream>>>(p0, Mbf, r0v);

  gemm_mfma<0><<<dim3(256, 13), 256, 0, stream>>>(Mbf, wihe_p, nullptr, GiAll, 256, 832);

  enc_all<<<256, 512, 0, stream>>>(GiAll, whhe_p, bih_e, bhh_e, Km, Cm, Bbf);
  accum_bwd<<<1024, 256, 0, stream>>>(Bbf, Km, Kmbf, Cm);
  wb_kernel<<<1024, 256, 0, stream>>>(Km, ba, wbv);
  gemm_mfma<0><<<dim3(256, 4), 256, 0, stream>>>(Kmbf, WaTb, nullptr, Ktl, 256, 256);

  build_xcat8<<<10240, 256, 0, stream>>>(cond, act, r0v, Mbf, xcat);
  gemm_mfma<1><<<dim3(1024, 4), 256, 0, stream>>>(xcat, W1b, b1, x1, 320, 256);
  gemm_mfma<1><<<dim3(1024, 4), 256, 0, stream>>>(x1, W2b, b2, x2, 256, 256);

  ushort* gic[2] = {GiC0, GiC1};
  gemm_mfma<0><<<dim3(256, 12), 256, 0, stream>>>(x2 + (size_t)0*16384*256, wihc_p, cbias, gic[0], 256, 768);
  gemm_mfma<0><<<dim3(256, 12), 256, 0, stream>>>(x2 + (size_t)1*16384*256, wihc_p, cbias, gic[1], 256, 768);
  cell_chunk<<<64, 512, 0, stream>>>(gic[0], whhc_p, bhh_c, hbuf,  0, hcT, out);
  gemm_mfma<0><<<dim3(256, 12), 256, 0, stream>>>(x2 + (size_t)2*16384*256, wihc_p, cbias, gic[0], 256, 768);
  cell_chunk<<<64, 512, 0, stream>>>(gic[1], whhc_p, bhh_c, hbuf, 16, hcT, out);
  gemm_mfma<0><<<dim3(256, 12), 256, 0, stream>>>(x2 + (size_t)3*16384*256, wihc_p, cbias, gic[1], 256, 768);
  cell_chunk<<<64, 512, 0, stream>>>(gic[0], whhc_p, bhh_c, hbuf, 32, hcT, out);
  cell_chunk<<<64, 512, 0, stream>>>(gic[1], whhc_p, bhh_c, hbuf, 48, hcT, out);

  v_out<<<16640, 256, 0, stream>>>(hcT, act, Wc, bc, out);
  attn_batch<<<1024, 256, 0, stream>>>(Ktl, hcT, wbv, Cm, p0, act, out);
}

// Round 12
// 1220.854 us; speedup vs baseline: 1.2612x; 1.2612x over previous
//
#include <hip/hip_runtime.h>
#include <hip/hip_bf16.h>
#include <cstddef>

#define T_ 64
#define N_ 1024
#define L_ 16
#define H_ 256
#define STATE_ 290
#define EKSTR 296   // enc hbf row stride (ushorts): 592B = 37*16, b128-aligned

typedef short s16x8 __attribute__((ext_vector_type(8)));
typedef float f32x4 __attribute__((ext_vector_type(4)));
typedef ushort us4 __attribute__((ext_vector_type(4)));
typedef ushort us8 __attribute__((ext_vector_type(8)));
#define MFMA16 __builtin_amdgcn_mfma_f32_16x16x32_bf16

// raw barrier: wait LDS ops only, do NOT drain global stores.
#define BAR() asm volatile("s_waitcnt lgkmcnt(0)\n\ts_barrier" ::: "memory")

__device__ __forceinline__ float b2f(ushort u){ return __uint_as_float(((unsigned)u) << 16); }
__device__ __forceinline__ ushort f2b(float f){
  unsigned x = __float_as_uint(f);
  return (ushort)((x + 0x7FFFu + ((x >> 16) & 1u)) >> 16);
}
__device__ __forceinline__ float gruh(float gir,float giz,float gig,
                                      float ghr,float ghz,float ghg,float hp){
  float r = 1.f/(1.f + __expf(-(gir + ghr)));
  float z = 1.f/(1.f + __expf(-(giz + ghz)));
  float g = tanhf(gig + r*ghg);
  return (1.f - z)*g + z*hp;
}

// ---------- conversion / prep kernels ----------
__global__ void conv_pad_b(const float* __restrict__ src, ushort* __restrict__ dst,
                           int R, int C, int Cp, int total){
  int idx = blockIdx.x*256 + threadIdx.x;
  if (idx >= total) return;
  int r = idx / Cp, c = idx - r*Cp;
  dst[idx] = (r < R && c < C) ? f2b(src[(size_t)r*C + c]) : (ushort)0;
}
__global__ void perm_enc_w(const float* __restrict__ src, ushort* __restrict__ dst,
                           int Ci, int Cp, int total){
  int idx = blockIdx.x*256 + threadIdx.x;
  if (idx >= total) return;
  int d = idx / Cp, c = idx - d*Cp;
  int tile = d >> 4, u = d & 15;
  int k = tile / 3, p = tile - 3*k;
  int hc = k*16 + u;
  bool ok = (tile < 51) && (hc < 257) && (c < Ci);
  dst[idx] = ok ? f2b(src[(size_t)(p*257 + hc)*Ci + c]) : (ushort)0;
}
__global__ void perm_cell_w(const float* __restrict__ src, ushort* __restrict__ dst){
  int idx = blockIdx.x*256 + threadIdx.x;
  if (idx >= 768*256) return;
  int d = idx >> 8, c = idx & 255;
  int tile = d >> 4, u = d & 15;
  int k = tile / 3, p = tile - 3*k;
  dst[idx] = f2b(src[(size_t)(p*256 + k*16 + u)*256 + c]);
}
__global__ void cbias_k(const float* __restrict__ bih, const float* __restrict__ bhh,
                        float* __restrict__ cb){
  int d = blockIdx.x*256 + threadIdx.x;
  if (d >= 768) return;
  int tile = d >> 4, u = d & 15;
  int k = tile / 3, p = tile - 3*k;
  int src = p*256 + k*16 + u;
  cb[d] = bih[src] + (p < 2 ? bhh[src] : 0.f);
}
__global__ void transp_b(const float* __restrict__ Wa, ushort* __restrict__ WaTb){
  int m = blockIdx.x, h = threadIdx.x;
  WaTb[(size_t)h*256 + m] = f2b(Wa[(size_t)m*256 + h]);
}
__global__ void embed_b(const int* __restrict__ lines, const float* __restrict__ emb,
                        ushort* __restrict__ Mbf){
  size_t idx = (size_t)blockIdx.x*256 + threadIdx.x;
  if (idx >= (size_t)N_*L_*H_) return;
  int c = idx & 255; size_t nl = idx >> 8;
  Mbf[idx] = f2b(emb[(size_t)lines[nl]*256 + c]);
}
__global__ void init_state(const float* __restrict__ hxs, float* __restrict__ hbuf,
                           float* __restrict__ p0){
  int n = blockIdx.x, t = threadIdx.x;
  __shared__ int nz;
  if (t == 0) nz = 0;
  __syncthreads();
  for (int c = t; c < STATE_; c += 256)
    if (hxs[(size_t)n*STATE_ + c] != 0.f) atomicOr(&nz, 1);
  __syncthreads();
  bool new_ep = (nz == 0);
  for (int c = t; c < H_; c += 256) hbuf[(size_t)n*H_ + c] = hxs[(size_t)n*STATE_ + 2 + c];
  if (t < L_) {
    float pv = hxs[(size_t)n*STATE_ + 2 + H_ + L_ + t];
    if (t == 0 && new_ep) pv = 1.f;
    p0[n*L_ + t] = pv;
  }
}
__global__ void r0_kernel(const float* __restrict__ p0, const ushort* __restrict__ Mbf,
                          float* __restrict__ r0v){
  int n = blockIdx.x, c = threadIdx.x;
  float s = 0.f;
  for (int l = 0; l < 16; ++l) s += p0[n*16 + l]*b2f(Mbf[((size_t)n*16 + l)*256 + c]);
  r0v[(size_t)n*256 + c] = s;
}
__global__ void build_xcat8(const float* __restrict__ cond, const int* __restrict__ act,
                            const float* __restrict__ r0v, const ushort* __restrict__ Mbf,
                            ushort* __restrict__ xcat){
  int idx = blockIdx.x*256 + threadIdx.x;
  if (idx >= T_*N_*40) return;
  int kc = idx % 40;
  int row = idx / 40;
  int n = row & 1023, t = row >> 10;
  us8 v;
  if (kc < 8) {
    const float* cp = cond + (size_t)row*64 + kc*8;
    #pragma unroll
    for (int i = 0; i < 8; ++i) v[i] = f2b(cp[i]);
  } else if (t == 0) {
    const float* rp = r0v + (size_t)n*256 + (kc-8)*8;
    #pragma unroll
    for (int i = 0; i < 8; ++i) v[i] = f2b(rp[i]);
  } else {
    int a = act[(size_t)(t-1)*1024 + n];
    v = *(const us8*)(Mbf + ((size_t)n*16 + a)*256 + (kc-8)*8);
  }
  *(us8*)(xcat + (size_t)idx*8) = v;
}

// ---------- MFMA GEMM: out[r,col] = act(sum_k A[r,k]*W[col,k] + bias[col]), bf16 out ----------
template<int RELU>
__global__ __launch_bounds__(256) void gemm_mfma(
    const ushort* __restrict__ A, const ushort* __restrict__ W,
    const float* __restrict__ bias, ushort* __restrict__ out,
    int Kd, int ldo){
  int lane = threadIdx.x & 63, wv = threadIdx.x >> 6;
  int u = lane & 15, g4 = lane >> 4;
  int br = blockIdx.x*64 + wv*16;
  int bm = blockIdx.y*64;
  const ushort* Arow = A + (size_t)(br + u)*Kd + g4*8;
  f32x4 acc0 = {0,0,0,0}, acc1 = {0,0,0,0}, acc2 = {0,0,0,0}, acc3 = {0,0,0,0};
  for (int k0 = 0; k0 < Kd; k0 += 32) {
    s16x8 av = *(const s16x8*)(Arow + k0);
    s16x8 b0 = *(const s16x8*)(W + (size_t)(bm +  0 + u)*Kd + k0 + g4*8);
    s16x8 b1 = *(const s16x8*)(W + (size_t)(bm + 16 + u)*Kd + k0 + g4*8);
    s16x8 b2 = *(const s16x8*)(W + (size_t)(bm + 32 + u)*Kd + k0 + g4*8);
    s16x8 b3 = *(const s16x8*)(W + (size_t)(bm + 48 + u)*Kd + k0 + g4*8);
    acc0 = MFMA16(av, b0, acc0, 0,0,0);
    acc1 = MFMA16(av, b1, acc1, 0,0,0);
    acc2 = MFMA16(av, b2, acc2, 0,0,0);
    acc3 = MFMA16(av, b3, acc3, 0,0,0);
  }
  f32x4 ac[4] = {acc0, acc1, acc2, acc3};
  #pragma unroll
  for (int mt = 0; mt < 4; ++mt) {
    int col = bm + mt*16 + u;
    float b = bias ? bias[col] : 0.f;
    #pragma unroll
    for (int r = 0; r < 4; ++r) {
      float v = ac[mt][r] + b;
      if (RELU) v = fmaxf(v, 0.f);
      out[(size_t)(br + g4*4 + r)*ldo + col] = f2b(v);
    }
  }
}

// ---------- unified encoder: fwd triangular chains + bwd chain in one kernel ----------
// 256 blocks (4 batch rows each) x 8 waves. amdgpu_waves_per_eu(2,2): tell the backend
// the real occupancy (LDS limits to 1 block/CU = 2 waves/EU) so it allocates up to 256
// VGPR instead of squeezing to 128 + spilling (rounds 10-11: 890MB scratch FETCH).
// Col-tiles processed in 2 sequential passes (acc 60 VGPR each) as structural insurance.
__global__ __launch_bounds__(512) __attribute__((amdgpu_waves_per_eu(2, 2))) void enc_all(
    const ushort* __restrict__ GiAll, const ushort* __restrict__ Wh,
    const float* __restrict__ bih, const float* __restrict__ bhh,
    float* __restrict__ Km, float* __restrict__ Cm, ushort* __restrict__ Bbf){
  __shared__ __align__(16) ushort hbf[2][80][EKSTR];   // 94,720 B
  __shared__ __align__(16) ushort gis[2][2][4][832];   // 26,624 B  [buf][fwd/bwd][nl][col]
  int tid = threadIdx.x, lane = tid & 63, wv = tid >> 6;
  int u = lane & 15, g4 = lane >> 4;
  int nb = blockIdx.x * 4;
  for (int i = tid; i < 2*80*EKSTR; i += 512) ((ushort*)hbf)[i] = 0;
  #pragma unroll
  for (int i0 = 0; i0 < 4; ++i0) {
    int i = tid + i0*512;
    if (i < 1664) {
      int flat = i*4;
      int fb = flat / 3328, rem = flat - fb*3328;
      int nl = rem / 832, k = rem - nl*832;
      int row = (nb+nl)*16 + (fb ? 15 : 0);
      *(us4*)&gis[0][fb][nl][k] = *(const us4*)(GiAll + (size_t)row*832 + k);
    }
  }
  BAR();
  int cur = 0;
  for (int j = 0; j < 16; ++j) {
    // prefetch next step's gi rows (fwd j+1, bwd 14-j) into the other buffer
    if (j < 15) {
      #pragma unroll
      for (int i0 = 0; i0 < 4; ++i0) {
        int i = tid + i0*512;
        if (i < 1664) {
          int flat = i*4;
          int fb = flat / 3328, rem = flat - fb*3328;
          int nl = rem / 832, k = rem - nl*832;
          int row = (nb+nl)*16 + (fb ? (14-j) : (j+1));
          *(us4*)&gis[cur^1][fb][nl][k] = *(const us4*)(GiAll + (size_t)row*832 + k);
        }
      }
    }
    // ---- two col-tile passes (register demand halved vs paired version) ----
    #pragma unroll 1
    for (int tt = 0; tt < 2; ++tt) {
      int kt = 2*wv + tt;
      f32x4 acc[5][3];
      #pragma unroll
      for (int rt = 0; rt < 5; ++rt) {
        acc[rt][0] = (f32x4){0,0,0,0};
        acc[rt][1] = (f32x4){0,0,0,0};
        acc[rt][2] = (f32x4){0,0,0,0};
      }
      #pragma unroll
      for (int q = 0; q < 9; ++q) {
        int off = q*32 + g4*8;
        s16x8 w0 = *(const s16x8*)(Wh + (size_t)((3*kt+0)*16 + u)*288 + off);
        s16x8 w1 = *(const s16x8*)(Wh + (size_t)((3*kt+1)*16 + u)*288 + off);
        s16x8 w2 = *(const s16x8*)(Wh + (size_t)((3*kt+2)*16 + u)*288 + off);
        #pragma unroll
        for (int rt = 0; rt < 5; ++rt) {
          if (rt < 4 && rt*4 > j) continue;
          s16x8 av = *(const s16x8*)&hbf[cur][rt*16 + u][off];
          acc[rt][0] = MFMA16(av, w0, acc[rt][0], 0,0,0);
          acc[rt][1] = MFMA16(av, w1, acc[rt][1], 0,0,0);
          acc[rt][2] = MFMA16(av, w2, acc[rt][2], 0,0,0);
        }
      }
      int c = kt*16 + u;                     // < 256 always here
      float bi0 = bih[c], bi1 = bih[257+c], bi2 = bih[514+c];
      float bh0 = bhh[c], bh1 = bhh[257+c], bh2 = bhh[514+c];
      float kmP[4] = {0.f, 0.f, 0.f, 0.f};
      #pragma unroll
      for (int rt = 0; rt < 4; ++rt) {
        int ii = rt*4 + g4;
        if (rt*4 <= j && ii <= j) {
          #pragma unroll
          for (int r = 0; r < 4; ++r) {
            int rowl = rt*16 + g4*4 + r;
            const ushort* gp = &gis[cur][0][r][3*kt*16];
            float hp = b2f(hbf[cur][rowl][c]);
            float h2 = gruh(b2f(gp[u]) + bi0, b2f(gp[16+u]) + bi1, b2f(gp[32+u]) + bi2,
                            acc[rt][0][r] + bh0, acc[rt][1][r] + bh1,
                            acc[rt][2][r] + bh2, hp);
            hbf[cur^1][rowl][c] = f2b(h2);
            kmP[r] += h2;
          }
        }
      }
      #pragma unroll
      for (int r = 0; r < 4; ++r) {
        float s = kmP[r];
        s += __shfl_xor(s, 16, 64);
        s += __shfl_xor(s, 32, 64);
        if (g4 == 0) Km[((size_t)(nb+r)*16 + j)*256 + c] = s;
      }
      if (g4 == 0) {   // bwd chain rows 64..67
        #pragma unroll
        for (int r = 0; r < 4; ++r) {
          const ushort* gp = &gis[cur][1][r][3*kt*16];
          float hp = b2f(hbf[cur][64 + r][c]);
          float h2 = gruh(b2f(gp[u]) + bi0, b2f(gp[16+u]) + bi1, b2f(gp[32+u]) + bi2,
                          acc[4][0][r] + bh0, acc[4][1][r] + bh1,
                          acc[4][2][r] + bh2, hp);
          hbf[cur^1][64 + r][c] = f2b(h2);
          Bbf[((size_t)j*1024 + nb + r)*288 + c] = f2b(h2);
        }
      }
    }
    // ---- tile16 (c=256): wave w handles row-tile w (w=0..3 fwd, w=4 bwd) ----
    if (wv < 5) {
      int rt = wv;
      bool go = (rt == 4) || (rt*4 <= j);
      if (go) {
        f32x4 a0 = {0,0,0,0}, a1 = {0,0,0,0}, a2 = {0,0,0,0};
        #pragma unroll
        for (int q = 0; q < 9; ++q) {
          int off = q*32 + g4*8;
          s16x8 w0 = *(const s16x8*)(Wh + (size_t)(48*16 + u)*288 + off);
          s16x8 w1 = *(const s16x8*)(Wh + (size_t)(49*16 + u)*288 + off);
          s16x8 w2 = *(const s16x8*)(Wh + (size_t)(50*16 + u)*288 + off);
          s16x8 av = *(const s16x8*)&hbf[cur][rt*16 + u][off];
          a0 = MFMA16(av, w0, a0, 0,0,0);
          a1 = MFMA16(av, w1, a1, 0,0,0);
          a2 = MFMA16(av, w2, a2, 0,0,0);
        }
        if (u == 0) {
          float bi0 = bih[256], bi1 = bih[513], bi2 = bih[770];
          float bh0 = bhh[256], bh1 = bhh[513], bh2 = bhh[770];
          if (rt < 4) {
            int ii = rt*4 + g4;
            if (ii <= j) {
              #pragma unroll
              for (int r = 0; r < 4; ++r) {
                int rowl = rt*16 + g4*4 + r;
                const ushort* gp = &gis[cur][0][r][768];
                float hp = b2f(hbf[cur][rowl][256]);
                float h2 = gruh(b2f(gp[0]) + bi0, b2f(gp[16]) + bi1, b2f(gp[32]) + bi2,
                                a0[r] + bh0, a1[r] + bh1, a2[r] + bh2, hp);
                hbf[cur^1][rowl][256] = f2b(h2);
                Cm[(size_t)(nb+r)*256 + ii*16 + j] = h2;
              }
            }
          } else if (g4 == 0) {
            #pragma unroll
            for (int r = 0; r < 4; ++r) {
              const ushort* gp = &gis[cur][1][r][768];
              float hp = b2f(hbf[cur][64 + r][256]);
              float h2 = gruh(b2f(gp[0]) + bi0, b2f(gp[16]) + bi1, b2f(gp[32]) + bi2,
                              a0[r] + bh0, a1[r] + bh1, a2[r] + bh2, hp);
              hbf[cur^1][64 + r][256] = f2b(h2);
              Bbf[((size_t)j*1024 + nb + r)*288 + 256] = f2b(h2);
            }
          }
        }
      }
    }
    BAR();
    cur ^= 1;
  }
}

// ---------- backward-part K accumulate + bf16 copy + C fill (i>j) ----------
__global__ void accum_bwd(const ushort* __restrict__ Bbf, float* __restrict__ Km,
                          ushort* __restrict__ Kmbf, float* __restrict__ Cm){
  int n = blockIdx.x, c = threadIdx.x;
  float s = 0.f;
  for (int jj = 15; jj >= 0; --jj) {
    if (jj < 15) s += b2f(Bbf[((size_t)(14-jj)*1024 + n)*288 + c]);
    size_t o = ((size_t)n*16 + jj)*256 + c;
    float v = Km[o] + s;
    Km[o] = v;
    Kmbf[o] = f2b(v);
  }
  int i = c >> 4, j = c & 15;
  if (i > j) Cm[(size_t)n*256 + i*16 + j] = b2f(Bbf[((size_t)(i-1-j)*1024 + n)*288 + 256]);
}
__global__ void wb_kernel(const float* __restrict__ Km, const float* __restrict__ ba,
                          float* __restrict__ wbv){
  int n = blockIdx.x, t = threadIdx.x;
  int l = t >> 4, lane = t & 15;
  float s = 0.f;
  for (int m = lane; m < 256; m += 16) s += Km[((size_t)n*16 + l)*256 + m]*ba[m];
  s += __shfl_down(s, 8, 16); s += __shfl_down(s, 4, 16);
  s += __shfl_down(s, 2, 16); s += __shfl_down(s, 1, 16);
  if (lane == 0) wbv[n*16 + l] = s;
}

// ---------- cell chunk: 16 t-steps, weight-stationary (Wh in VGPRs) ----------
// amdgpu_waves_per_eu(2,2): 256-VGPR budget so the 192-VGPR weight preload stays
// resident (the 128-VGPR default silently spilled it in rounds 7-11).
__global__ __launch_bounds__(512) __attribute__((amdgpu_waves_per_eu(2, 2))) void cell_chunk(
    const ushort* __restrict__ Gi, const ushort* __restrict__ Wh,
    const float* __restrict__ bhh, const float* __restrict__ hbuf,
    int t0, ushort* __restrict__ hcT, float* __restrict__ out){
  __shared__ __align__(16) ushort hbf[2][16][266];
  int tid = threadIdx.x, lane = tid & 63, wv = tid >> 6;
  int u = lane & 15, g4 = lane >> 4;
  int n0 = blockIdx.x * 16;
  int ktA = wv, ktB = wv + 8;
  int cA = ktA*16 + u, cB = ktB*16 + u;
  s16x8 WA0[8], WA1[8], WA2[8], WB0[8], WB1[8], WB2[8];
  #pragma unroll
  for (int q = 0; q < 8; ++q) {
    int off = q*32 + g4*8;
    WA0[q] = *(const s16x8*)(Wh + (size_t)((3*ktA+0)*16 + u)*256 + off);
    WA1[q] = *(const s16x8*)(Wh + (size_t)((3*ktA+1)*16 + u)*256 + off);
    WA2[q] = *(const s16x8*)(Wh + (size_t)((3*ktA+2)*16 + u)*256 + off);
    WB0[q] = *(const s16x8*)(Wh + (size_t)((3*ktB+0)*16 + u)*256 + off);
    WB1[q] = *(const s16x8*)(Wh + (size_t)((3*ktB+1)*16 + u)*256 + off);
    WB2[q] = *(const s16x8*)(Wh + (size_t)((3*ktB+2)*16 + u)*256 + off);
  }
  float bhgA = bhh[512 + cA], bhgB = bhh[512 + cB];
  if (t0 == 0) {
    for (int i = tid; i < 16*256; i += 512) {
      int rr = i >> 8, cc = i & 255;
      hbf[0][rr][cc] = f2b(hbuf[(size_t)(n0 + rr)*256 + cc]);
    }
  } else {
    for (int i = tid; i < 16*256; i += 512) {
      int rr = i >> 8, cc = i & 255;
      hbf[0][rr][cc] = hcT[((size_t)(t0-1)*1024 + n0 + rr)*256 + cc];
    }
  }
  BAR();
  int cur = 0;
  for (int s = 0; s < 16; ++s) {
    int t = t0 + s;
    f32x4 a0={0,0,0,0},a1={0,0,0,0},a2={0,0,0,0};
    f32x4 b0={0,0,0,0},b1={0,0,0,0},b2={0,0,0,0};
    #pragma unroll
    for (int q = 0; q < 8; ++q) {
      s16x8 ah = *(const s16x8*)&hbf[cur][u][q*32 + g4*8];
      a0 = MFMA16(ah, WA0[q], a0, 0,0,0);
      a1 = MFMA16(ah, WA1[q], a1, 0,0,0);
      a2 = MFMA16(ah, WA2[q], a2, 0,0,0);
      b0 = MFMA16(ah, WB0[q], b0, 0,0,0);
      b1 = MFMA16(ah, WB1[q], b1, 0,0,0);
      b2 = MFMA16(ah, WB2[q], b2, 0,0,0);
    }
    const ushort* gbase = Gi + (size_t)s*1024*768;
    #pragma unroll
    for (int r = 0; r < 4; ++r) {
      int row = g4*4 + r;
      const ushort* gr = gbase + (size_t)(n0 + row)*768;
      {
        float gir = b2f(gr[3*ktA*16 + u]);
        float giz = b2f(gr[3*ktA*16 + 16 + u]);
        float gig = b2f(gr[3*ktA*16 + 32 + u]);
        float hp  = b2f(hbf[cur][row][cA]);
        float rr2 = 1.f/(1.f + __expf(-(gir + a0[r])));
        float zz  = 1.f/(1.f + __expf(-(giz + a1[r])));
        float ex  = __expf(2.f*(gig + rr2*(a2[r] + bhgA)));
        float gg  = 1.f - 2.f/(ex + 1.f);
        float h2  = (1.f - zz)*gg + zz*hp;
        ushort hb = f2b(h2);
        hbf[cur^1][row][cA] = hb;
        hcT[((size_t)t*1024 + n0 + row)*256 + cA] = hb;
        out[((size_t)t*1024 + n0 + row)*STATE_ + 2 + cA] = h2;
        if (t == 63) out[((size_t)64*1024 + n0 + row)*STATE_ + 2 + cA] = h2;
      }
      {
        float gir = b2f(gr[3*ktB*16 + u]);
        float giz = b2f(gr[3*ktB*16 + 16 + u]);
        float gig = b2f(gr[3*ktB*16 + 32 + u]);
        float hp  = b2f(hbf[cur][row][cB]);
        float rr2 = 1.f/(1.f + __expf(-(gir + b0[r])));
        float zz  = 1.f/(1.f + __expf(-(giz + b1[r])));
        float ex  = __expf(2.f*(gig + rr2*(b2[r] + bhgB)));
        float gg  = 1.f - 2.f/(ex + 1.f);
        float h2  = (1.f - zz)*gg + zz*hp;
        ushort hb = f2b(h2);
        hbf[cur^1][row][cB] = hb;
        hcT[((size_t)t*1024 + n0 + row)*256 + cB] = hb;
        out[((size_t)t*1024 + n0 + row)*STATE_ + 2 + cB] = h2;
        if (t == 63) out[((size_t)64*1024 + n0 + row)*STATE_ + 2 + cB] = h2;
      }
    }
    BAR();
    cur ^= 1;
  }
}

// ---------- v & a columns: one wave per output row ----------
__global__ __launch_bounds__(256) void v_out(
    const ushort* __restrict__ hcT, const int* __restrict__ act,
    const float* __restrict__ Wc, const float* __restrict__ bc,
    float* __restrict__ out){
  int rowid = blockIdx.x*4 + (threadIdx.x >> 6);
  if (rowid >= 65*1024) return;
  int lane = threadIdx.x & 63;
  int tt = rowid >> 10, n = rowid & 1023;
  int t = tt > 63 ? 63 : tt;
  us4 hv = *(const us4*)(hcT + ((size_t)t*1024 + n)*256 + lane*4);
  f32x4 wv4 = *(const f32x4*)(Wc + lane*4);
  float s = b2f(hv[0])*wv4[0] + b2f(hv[1])*wv4[1] + b2f(hv[2])*wv4[2] + b2f(hv[3])*wv4[3];
  #pragma unroll
  for (int off = 32; off > 0; off >>= 1) s += __shfl_xor(s, off, 64);
  if (lane == 0) {
    size_t ro = (size_t)rowid*STATE_;
    out[ro]     = (float)act[(size_t)t*1024 + n];
    out[ro + 1] = s + bc[0];
  }
}

// ---------- batched attention/softmax post-pass ----------
__global__ __launch_bounds__(256) void attn_batch(
    const ushort* __restrict__ Ktl, const ushort* __restrict__ hcT,
    const float* __restrict__ wbv, const float* __restrict__ Cm,
    const float* __restrict__ p0, const int* __restrict__ act,
    float* __restrict__ out){
  int n = blockIdx.x;
  int lane = threadIdx.x & 63, wv = threadIdx.x >> 6;
  int u = lane & 15, g4 = lane >> 4;
  int t0 = wv*16;
  const ushort* Ka = Ktl + ((size_t)n*16 + u)*256 + g4*8;
  const ushort* Hb = hcT + ((size_t)(t0 + u)*1024 + n)*256 + g4*8;
  f32x4 acc = {0,0,0,0};
  #pragma unroll
  for (int q = 0; q < 8; ++q) {
    s16x8 av = *(const s16x8*)(Ka + q*32);
    s16x8 bv = *(const s16x8*)(Hb + q*32);
    acc = MFMA16(av, bv, acc, 0,0,0);
  }
  int t = t0 + u;
  float ps[4];
  if (t == 0) {
    #pragma unroll
    for (int r = 0; r < 4; ++r) {
      float catt = 0.f;
      for (int i = 0; i < 16; ++i) catt += p0[n*16 + i]*Cm[(size_t)n*256 + i*16 + g4*4 + r];
      ps[r] = (acc[r] + wbv[n*16 + g4*4 + r]) * catt;
    }
  } else {
    int ap = act[(size_t)(t-1)*1024 + n];
    #pragma unroll
    for (int r = 0; r < 4; ++r)
      ps[r] = (acc[r] + wbv[n*16 + g4*4 + r]) * Cm[(size_t)n*256 + ap*16 + g4*4 + r];
  }
  float mx = fmaxf(fmaxf(ps[0], ps[1]), fmaxf(ps[2], ps[3]));
  mx = fmaxf(mx, __shfl_xor(mx, 16, 64));
  mx = fmaxf(mx, __shfl_xor(mx, 32, 64));
  float e[4], se = 0.f;
  #pragma unroll
  for (int r = 0; r < 4; ++r) { e[r] = __expf(ps[r] - mx); se += e[r]; }
  se += __shfl_xor(se, 16, 64);
  se += __shfl_xor(se, 32, 64);
  float inv = 1.f/se;
  int a = act[(size_t)t*1024 + n];
  size_t ro = ((size_t)t*1024 + n)*STATE_;
  #pragma unroll
  for (int r = 0; r < 4; ++r) {
    out[ro + 258 + g4*4 + r] = e[r]*inv;
    out[ro + 274 + g4*4 + r] = (g4*4 + r == a) ? 1.f : 0.f;
  }
  if (t == 63) {
    size_t r2 = ((size_t)64*1024 + n)*STATE_;
    #pragma unroll
    for (int r = 0; r < 4; ++r) {
      out[r2 + 258 + g4*4 + r] = e[r]*inv;
      out[r2 + 274 + g4*4 + r] = (g4*4 + r == a) ? 1.f : 0.f;
    }
  }
}

extern "C" void kernel_launch(void* const* d_in, const int* in_sizes, int n_in,
                              void* d_out, int out_size, void* d_ws, size_t ws_size,
                              hipStream_t stream){
  (void)in_sizes; (void)n_in; (void)out_size; (void)ws_size;
  const float* cond  = (const float*)d_in[0];
  const int*   lines = (const int*)  d_in[1];
  const int*   act   = (const int*)  d_in[2];
  const float* hxs   = (const float*)d_in[3];
  const float* emb   = (const float*)d_in[4];
  const float* wih_e = (const float*)d_in[5];
  const float* whh_e = (const float*)d_in[6];
  const float* bih_e = (const float*)d_in[7];
  const float* bhh_e = (const float*)d_in[8];
  const float* W1    = (const float*)d_in[9];
  const float* b1    = (const float*)d_in[10];
  const float* W2    = (const float*)d_in[11];
  const float* b2    = (const float*)d_in[12];
  const float* wih_c = (const float*)d_in[13];
  const float* whh_c = (const float*)d_in[14];
  const float* bih_c = (const float*)d_in[15];
  const float* bhh_c = (const float*)d_in[16];
  const float* Wa    = (const float*)d_in[17];
  const float* ba    = (const float*)d_in[18];
  const float* Wc    = (const float*)d_in[19];
  const float* bc    = (const float*)d_in[20];
  float* out = (float*)d_out;

  char* base = (char*)d_ws;
  ushort* Mbf    = (ushort*)(base + 0);             // [16384,256]       P0-P3
  ushort* Bbf    = (ushort*)(base + 8388608);       // [16,1024,288]     P1-P2
  float*  Km     = (float*) (base + 17825792);      // [16384,256] f32   P1-P2
  ushort* Kmbf   = (ushort*)(base + 34603008);      // [16384,256]       P2
  ushort* xcat   = (ushort*)(base + 8388608);       // [65536,320]       P3
  ushort* x2     = (ushort*)(base + 8388608);       // [65536,256]       P3
  ushort* hcT    = (ushort*)(base + 8388608);       // [64,1024,256]     P4-P5
  ushort* GiAll  = (ushort*)(base + 50331648);      // [16384,832]       P1
  ushort* x1     = (ushort*)(base + 50331648);      // [65536,256]       P3
  ushort* GiC0   = (ushort*)(base + 50331648);      // [16,1024,768]     P4
  ushort* GiC1   = (ushort*)(base + 75497472);      // [16,1024,768]     P4
  ushort* Ktl    = (ushort*)(base + 100663296);     // [16384,256]       P2-P5
  float*  Cm     = (float*) (base + 109051904);     // [1024,16,16]
  float*  hbuf   = (float*) (base + 110100480);     // [1024,256]
  float*  p0     = (float*) (base + 111149056);     // [1024,16]
  float*  r0v    = (float*) (base + 111214592);     // [1024,256]
  float*  wbv    = (float*) (base + 112263168);     // [1024,16]
  ushort* wihe_p = (ushort*)(base + 112328704);     // [832,256]
  ushort* whhe_p = (ushort*)(base + 112754688);     // [832,288]
  ushort* wihc_p = (ushort*)(base + 113233920);     // [768,256]
  ushort* whhc_p = (ushort*)(base + 113627136);     // [768,256]
  ushort* W1b    = (ushort*)(base + 114020352);     // [256,320]
  ushort* W2b    = (ushort*)(base + 114184192);     // [256,256]
  ushort* WaTb   = (ushort*)(base + 114315264);     // [256,256]
  float*  cbias  = (float*) (base + 114446336);     // [768]

  perm_enc_w<<<832, 256, 0, stream>>>(wih_e, wihe_p, 256, 256, 832*256);
  perm_enc_w<<<936, 256, 0, stream>>>(whh_e, whhe_p, 257, 288, 832*288);
  perm_cell_w<<<768, 256, 0, stream>>>(wih_c, wihc_p);
  perm_cell_w<<<768, 256, 0, stream>>>(whh_c, whhc_p);
  cbias_k<<<3, 256, 0, stream>>>(bih_c, bhh_c, cbias);
  conv_pad_b<<<320, 256, 0, stream>>>(W1, W1b, 256, 320, 320, 256*320);
  conv_pad_b<<<256, 256, 0, stream>>>(W2, W2b, 256, 256, 256, 256*256);
  transp_b<<<256, 256, 0, stream>>>(Wa, WaTb);

  embed_b<<<16384, 256, 0, stream>>>(lines, emb, Mbf);
  init_state<<<1024, 256, 0, stream>>>(hxs, hbuf, p0);
  r0_kernel<<<1024, 256, 0, stream>>>(p0, Mbf, r0v);

  gemm_mfma<0><<<dim3(256, 13), 256, 0, stream>>>(Mbf, wihe_p, nullptr, GiAll, 256, 832);

  enc_all<<<256, 512, 0, stream>>>(GiAll, whhe_p, bih_e, bhh_e, Km, Cm, Bbf);
  accum_bwd<<<1024, 256, 0, stream>>>(Bbf, Km, Kmbf, Cm);
  wb_kernel<<<1024, 256, 0, stream>>>(Km, ba, wbv);
  gemm_mfma<0><<<dim3(256, 4), 256, 0, stream>>>(Kmbf, WaTb, nullptr, Ktl, 256, 256);

  build_xcat8<<<10240, 256, 0, stream>>>(cond, act, r0v, Mbf, xcat);
  gemm_mfma<1><<<dim3(1024, 4), 256, 0, stream>>>(xcat, W1b, b1, x1, 320, 256);
  gemm_mfma<1><<<dim3(1024, 4), 256, 0, stream>>>(x1, W2b, b2, x2, 256, 256);

  ushort* gic[2] = {GiC0, GiC1};
  gemm_mfma<0><<<dim3(256, 12), 256, 0, stream>>>(x2 + (size_t)0*16384*256, wihc_p, cbias, gic[0], 256, 768);
  gemm_mfma<0><<<dim3(256, 12), 256, 0, stream>>>(x2 + (size_t)1*16384*256, wihc_p, cbias, gic[1], 256, 768);
  cell_chunk<<<64, 512, 0, stream>>>(gic[0], whhc_p, bhh_c, hbuf,  0, hcT, out);
  gemm_mfma<0><<<dim3(256, 12), 256, 0, stream>>>(x2 + (size_t)2*16384*256, wihc_p, cbias, gic[0], 256, 768);
  cell_chunk<<<64, 512, 0, stream>>>(gic[1], whhc_p, bhh_c, hbuf, 16, hcT, out);
  gemm_mfma<0><<<dim3(256, 12), 256, 0, stream>>>(x2 + (size_t)3*16384*256, wihc_p, cbias, gic[1], 256, 768);
  cell_chunk<<<64, 512, 0, stream>>>(gic[0], whhc_p, bhh_c, hbuf, 32, hcT, out);
  cell_chunk<<<64, 512, 0, stream>>>(gic[1], whhc_p, bhh_c, hbuf, 48, hcT, out);

  v_out<<<16640, 256, 0, stream>>>(hcT, act, Wc, bc, out);
  attn_batch<<<1024, 256, 0, stream>>>(Ktl, hcT, wbv, Cm, p0, act, out);
}